// Round 7
// baseline (741.481 us; speedup 1.0000x reference)
//
#include <hip/hip_runtime.h>

// Problem constants (B=64, L=512, H=1024)
constexpr int BB = 64;
constexpr int LL = 512;
constexpr int HH = 1024;
constexpr int SPLITS = 16;            // split-K factor for all GEMMs
constexpr int NTHR  = 256;
constexpr int NWORK_GEMM = 3 * 16 * SPLITS;   // 768 (r, n-tile, split) tiles

typedef float nt_float4 __attribute__((ext_vector_type(4)));

struct Args {
    const float* hs; const float* ho; const float* ha; const float* enc;
    const int* Fp;
    const float* W_as;  const float* W_so;  const float* W_oa;
    const float* Win_as; const float* Win_so; const float* Win_oa;
    const float* Wout_as; const float* Wout_so; const float* Wout_oa;
    float* part; float* hx; float* tt; float* wc; float* opm; float* ms;
    int* cnt;                          // [256] semaphores, zeroed per launch
    float* out;
};

// ---------------------------------------------------------------------------
// One (r, n-tile, split) tile of the skinny GEMM, software-pipelined
// (register prefetch of next K-step). smem: As[32][64]+Ws[32][64] = 16 KB.
// ---------------------------------------------------------------------------
template<int K0, int K1>
__device__ __forceinline__ void gemm_tile(const float* __restrict__ a0,
                                          const float* __restrict__ a1,
                                          const float* __restrict__ w,
                                          float* __restrict__ part_r,
                                          int nt, int sp, int tid,
                                          float (*As)[64], float (*Ws)[64])
{
    constexpr int K = K0 + K1;
    constexpr int KRANGE = K / SPLITS;
    const int n0 = nt << 6;
    const int ks = sp * KRANGE;
    const int tn = tid & 15;           // n quad index
    const int tm = tid >> 4;           // m quad index
    const int m   = tid >> 2;          // A-stage row 0..63
    const int kk0 = (tid & 3) << 3;    // A-stage k offset 0,8,16,24
    const int j4  = (tid & 15) << 2;   // W-stage col offset
    const int kkw = tid >> 4;          // W-stage k row 0..15

    float4 av0, av1, wv0, wv1;
    {
        const int kg = ks + kk0;
        const float* srcA = (K1 == 0 || kg < K0) ? (a0 + (size_t)m * HH + kg)
                                                 : (a1 + (size_t)m * HH + (kg - K0));
        av0 = *(const float4*)srcA;
        av1 = *(const float4*)(srcA + 4);
        wv0 = *(const float4*)(w + (size_t)(ks + kkw) * HH + n0 + j4);
        wv1 = *(const float4*)(w + (size_t)(ks + kkw + 16) * HH + n0 + j4);
    }

    float acc[4][4] = {};

    for (int kt = ks; kt < ks + KRANGE; kt += 32) {
        As[kk0 + 0][m] = av0.x; As[kk0 + 1][m] = av0.y;
        As[kk0 + 2][m] = av0.z; As[kk0 + 3][m] = av0.w;
        As[kk0 + 4][m] = av1.x; As[kk0 + 5][m] = av1.y;
        As[kk0 + 6][m] = av1.z; As[kk0 + 7][m] = av1.w;
        *(float4*)&Ws[kkw][j4]      = wv0;
        *(float4*)&Ws[kkw + 16][j4] = wv1;
        __syncthreads();

        if (kt + 32 < ks + KRANGE) {
            const int kn = kt + 32;
            const int kg = kn + kk0;
            const float* srcA = (K1 == 0 || kg < K0) ? (a0 + (size_t)m * HH + kg)
                                                     : (a1 + (size_t)m * HH + (kg - K0));
            av0 = *(const float4*)srcA;
            av1 = *(const float4*)(srcA + 4);
            wv0 = *(const float4*)(w + (size_t)(kn + kkw) * HH + n0 + j4);
            wv1 = *(const float4*)(w + (size_t)(kn + kkw + 16) * HH + n0 + j4);
        }

        #pragma unroll
        for (int kk = 0; kk < 32; kk++) {
            float4 a4 = *(const float4*)&As[kk][tm << 2];
            float4 b4 = *(const float4*)&Ws[kk][tn << 2];
            float av[4] = {a4.x, a4.y, a4.z, a4.w};
            float bv[4] = {b4.x, b4.y, b4.z, b4.w};
            #pragma unroll
            for (int i = 0; i < 4; i++)
                #pragma unroll
                for (int j = 0; j < 4; j++)
                    acc[i][j] += av[i] * bv[j];
        }
        __syncthreads();
    }

    float* dst = part_r + (size_t)(sp << 6) * HH + n0 + (tn << 2);
    #pragma unroll
    for (int i = 0; i < 4; i++) {
        const int mm = (tm << 2) + i;
        *(float4*)(dst + (size_t)mm * HH) = make_float4(acc[i][0], acc[i][1], acc[i][2], acc[i][3]);
    }
}

// ---------------------------------------------------------------------------
// Split-K epilogue helpers: thread owns (m = tid>>2, 16 cols at c0).
// ---------------------------------------------------------------------------
__device__ __forceinline__ void reduce_sums(const float* p,
                                            float4& s0, float4& s1,
                                            float4& s2, float4& s3)
{
    s0 = *(const float4*)(p + 0);  s1 = *(const float4*)(p + 4);
    s2 = *(const float4*)(p + 8);  s3 = *(const float4*)(p + 12);
    #pragma unroll 4
    for (int sp = 1; sp < SPLITS; sp++) {
        const float* q = p + (size_t)sp * 65536;
        float4 t;
        t = *(const float4*)(q + 0);  s0.x += t.x; s0.y += t.y; s0.z += t.z; s0.w += t.w;
        t = *(const float4*)(q + 4);  s1.x += t.x; s1.y += t.y; s1.z += t.z; s1.w += t.w;
        t = *(const float4*)(q + 8);  s2.x += t.x; s2.y += t.y; s2.z += t.z; s2.w += t.w;
        t = *(const float4*)(q + 12); s3.x += t.x; s3.y += t.y; s3.z += t.z; s3.w += t.w;
    }
}

__device__ __forceinline__ void tanh4(float4& v)
{
    v.x = tanhf(v.x); v.y = tanhf(v.y); v.z = tanhf(v.z); v.w = tanhf(v.w);
}

// Sum 16 splits of one 64x64 tile -> dst (optional tanh).
__device__ __forceinline__ void reduce_tile_store(const float* part_r, float* dst_r,
                                                  int n0, int tid, bool do_tanh)
{
    const int m  = tid >> 2;
    const int c0 = n0 + ((tid & 3) << 4);
    const float* p = part_r + (size_t)m * HH + c0;
    float4 s0, s1, s2, s3;
    reduce_sums(p, s0, s1, s2, s3);
    if (do_tanh) { tanh4(s0); tanh4(s1); tanh4(s2); tanh4(s3); }
    float* d = dst_r + (size_t)m * HH + c0;
    *(float4*)(d + 0) = s0; *(float4*)(d + 4)  = s1;
    *(float4*)(d + 8) = s2; *(float4*)(d + 12) = s3;
}

// Sum 16 splits + tanh + broadcast F copies -> out[r][m][f][*].
__device__ __forceinline__ void reduce_tile_bcast(const Args& a, int r, int n0, int tid)
{
    const int m  = tid >> 2;
    const int c0 = n0 + ((tid & 3) << 4);
    const float* p = a.part + (size_t)r * SPLITS * 65536 + (size_t)m * HH + c0;
    float4 s0, s1, s2, s3;
    reduce_sums(p, s0, s1, s2, s3);
    tanh4(s0); tanh4(s1); tanh4(s2); tanh4(s3);

    nt_float4 v0, v1, v2, v3;
    v0.x = s0.x; v0.y = s0.y; v0.z = s0.z; v0.w = s0.w;
    v1.x = s1.x; v1.y = s1.y; v1.z = s1.z; v1.w = s1.w;
    v2.x = s2.x; v2.y = s2.y; v2.z = s2.z; v2.w = s2.w;
    v3.x = s3.x; v3.y = s3.y; v3.z = s3.z; v3.w = s3.w;

    const int F = *a.Fp;
    float* o = a.out + ((size_t)(r * BB + m) * F) * HH + c0;
    for (int f = 0; f < F; f++) {
        float* of = o + (size_t)f * HH;
        __builtin_nontemporal_store(v0, (nt_float4*)(of + 0));
        __builtin_nontemporal_store(v1, (nt_float4*)(of + 4));
        __builtin_nontemporal_store(v2, (nt_float4*)(of + 8));
        __builtin_nontemporal_store(v3, (nt_float4*)(of + 12));
    }
}

// ---------------------------------------------------------------------------
// Flash attention chunk: 64 l-rows (chunk = b*8 + lc), wave handles 4 rows x
// 4 iterations. LDS: o_l[4][1024] (16 KB) + ms_sh[4][3][2]. Per-relation
// cross-wave merge. (Verbatim round-2 correctness-proven version.)
// ---------------------------------------------------------------------------
__device__ __forceinline__ void flash_phase(const Args& args, int chunk, int tid,
                                            float* smem)
{
    float (*o_l)[HH]     = (float(*)[HH])smem;            // [4][1024], 16 KB
    float (*ms_sh)[3][2] = (float(*)[3][2])(smem + 4096); // [4][3][2]
    const int b    = chunk >> 3;
    const int lc   = chunk & 7;
    const int lane = tid & 63;
    const int wv   = tid >> 6;

    float4 tr[3][4];
    #pragma unroll
    for (int r = 0; r < 3; r++)
        #pragma unroll
        for (int v = 0; v < 4; v++)
            tr[r][v] = *(const float4*)&args.tt[(size_t)(r * BB + b) * HH + (lane << 2) + (v << 8)];

    float  m_run[3] = {-3.0e38f, -3.0e38f, -3.0e38f};
    float  S_run[3] = {0.f, 0.f, 0.f};
    float4 o_run[3][4];
    #pragma unroll
    for (int r = 0; r < 3; r++)
        #pragma unroll
        for (int v = 0; v < 4; v++)
            o_run[r][v] = make_float4(0.f, 0.f, 0.f, 0.f);

    const float* ebase = args.enc + ((size_t)b * LL + (lc << 6) + (wv << 2)) * HH + (lane << 2);

    for (int it = 0; it < 4; it++) {
        const float* e = ebase + (size_t)(it << 4) * HH;
        float4 ev[4][4];
        #pragma unroll
        for (int j = 0; j < 4; j++)
            #pragma unroll
            for (int v = 0; v < 4; v++)
                ev[j][v] = *(const float4*)(e + (size_t)j * HH + (v << 8));

        float s[3][4];
        #pragma unroll
        for (int j = 0; j < 4; j++) {
            float d0 = 0.f, d1 = 0.f, d2 = 0.f;
            #pragma unroll
            for (int v = 0; v < 4; v++) {
                const float4 x = ev[j][v];
                d0 += x.x * tr[0][v].x + x.y * tr[0][v].y + x.z * tr[0][v].z + x.w * tr[0][v].w;
                d1 += x.x * tr[1][v].x + x.y * tr[1][v].y + x.z * tr[1][v].z + x.w * tr[1][v].w;
                d2 += x.x * tr[2][v].x + x.y * tr[2][v].y + x.z * tr[2][v].z + x.w * tr[2][v].w;
            }
            #pragma unroll
            for (int off = 32; off > 0; off >>= 1) {
                d0 += __shfl_xor(d0, off);
                d1 += __shfl_xor(d1, off);
                d2 += __shfl_xor(d2, off);
            }
            s[0][j] = d0; s[1][j] = d1; s[2][j] = d2;
        }

        #pragma unroll
        for (int r = 0; r < 3; r++) {
            const float mb = fmaxf(fmaxf(s[r][0], s[r][1]), fmaxf(s[r][2], s[r][3]));
            const float mn_ = fmaxf(m_run[r], mb);
            const float alpha = __expf(m_run[r] - mn_);
            m_run[r] = mn_;
            float p[4];
            float psum = 0.f;
            #pragma unroll
            for (int j = 0; j < 4; j++) { p[j] = __expf(s[r][j] - mn_); psum += p[j]; }
            S_run[r] = S_run[r] * alpha + psum;
            #pragma unroll
            for (int v = 0; v < 4; v++) {
                float4 o = o_run[r][v];
                o.x *= alpha; o.y *= alpha; o.z *= alpha; o.w *= alpha;
                #pragma unroll
                for (int j = 0; j < 4; j++) {
                    const float4 x = ev[j][v];
                    o.x += p[j] * x.x; o.y += p[j] * x.y;
                    o.z += p[j] * x.z; o.w += p[j] * x.w;
                }
                o_run[r][v] = o;
            }
        }
    }

    __syncthreads();
    if (lane == 0) {
        #pragma unroll
        for (int r = 0; r < 3; r++) { ms_sh[wv][r][0] = m_run[r]; ms_sh[wv][r][1] = S_run[r]; }
    }

    #pragma unroll
    for (int r = 0; r < 3; r++) {
        __syncthreads();
        #pragma unroll
        for (int v = 0; v < 4; v++)
            *(float4*)&o_l[wv][(lane << 2) + (v << 8)] = o_run[r][v];
        __syncthreads();

        const float m0 = ms_sh[0][r][0], m1 = ms_sh[1][r][0];
        const float m2 = ms_sh[2][r][0], m3 = ms_sh[3][r][0];
        const float M = fmaxf(fmaxf(m0, m1), fmaxf(m2, m3));
        const float w0 = __expf(m0 - M), w1 = __expf(m1 - M);
        const float w2 = __expf(m2 - M), w3 = __expf(m3 - M);
        float4 q0 = *(const float4*)&o_l[0][tid << 2];
        float4 q1 = *(const float4*)&o_l[1][tid << 2];
        float4 q2 = *(const float4*)&o_l[2][tid << 2];
        float4 q3 = *(const float4*)&o_l[3][tid << 2];
        float4 acc;
        acc.x = w0 * q0.x + w1 * q1.x + w2 * q2.x + w3 * q3.x;
        acc.y = w0 * q0.y + w1 * q1.y + w2 * q2.y + w3 * q3.y;
        acc.z = w0 * q0.z + w1 * q1.z + w2 * q2.z + w3 * q3.z;
        acc.w = w0 * q0.w + w1 * q1.w + w2 * q2.w + w3 * q3.w;
        *(float4*)&args.opm[((size_t)chunk * 3 + r) * HH + (tid << 2)] = acc;
        if (tid == 0) {
            const float S = w0 * ms_sh[0][r][1] + w1 * ms_sh[1][r][1]
                          + w2 * ms_sh[2][r][1] + w3 * ms_sh[3][r][1];
            args.ms[((size_t)chunk * 3 + r) * 2 + 0] = M;
            args.ms[((size_t)chunk * 3 + r) * 2 + 1] = S;
        }
    }
}

// ---------------------------------------------------------------------------
// LSE-combine 8 chunks of one (b, r) -> wc. Thread owns h = tid*4.
// ---------------------------------------------------------------------------
__device__ __forceinline__ void combine8(const Args& args, int b, int r, int tid)
{
    float mv[8], sv[8];
    float M = -3.0e38f;
    #pragma unroll
    for (int c = 0; c < 8; c++) {
        const int chunk = (b << 3) + c;
        mv[c] = args.ms[((size_t)chunk * 3 + r) * 2 + 0];
        sv[c] = args.ms[((size_t)chunk * 3 + r) * 2 + 1];
        M = fmaxf(M, mv[c]);
    }
    float S = 0.f;
    float4 acc = make_float4(0.f, 0.f, 0.f, 0.f);
    #pragma unroll
    for (int c = 0; c < 8; c++) {
        const float wgt = __expf(mv[c] - M);
        S += wgt * sv[c];
        const int chunk = (b << 3) + c;
        float4 q = *(const float4*)&args.opm[((size_t)chunk * 3 + r) * HH + (tid << 2)];
        acc.x += wgt * q.x; acc.y += wgt * q.y;
        acc.z += wgt * q.z; acc.w += wgt * q.w;
    }
    const float inv = 1.0f / S;
    acc.x *= inv; acc.y *= inv; acc.z *= inv; acc.w *= inv;
    *(float4*)&args.wc[(size_t)(r * BB + b) * HH + (tid << 2)] = acc;
}

// ---------------------------------------------------------------------------
// Fused kernels: split-K semaphore epilogue (canonical threadfence-reduction
// pattern: store -> __threadfence -> __syncthreads -> atomic -> last block
// acquires with __threadfence and reduces). No co-residency or dispatch-order
// assumption: ANY arrival order works; the 16th arrival does the epilogue.
// ---------------------------------------------------------------------------
__global__ __launch_bounds__(NTHR)
void k_gemmA_red(Args a)
{
    __shared__ __align__(16) float smem[4096];
    __shared__ int lastFlag;
    const int wk = blockIdx.x, tid = threadIdx.x;
    const int r = wk >> 8, nt = wk & 15, sp = (wk >> 4) & 15;
    const float* a0 = (r == 0) ? a.ha : (r == 1) ? a.hs : a.ho;
    const float* a1 = (r == 0) ? a.hs : (r == 1) ? a.ho : a.ha;
    const float* w  = (r == 0) ? a.W_as : (r == 1) ? a.W_so : a.W_oa;
    gemm_tile<1024, 1024>(a0, a1, w, a.part + (size_t)r * SPLITS * 65536,
                          nt, sp, tid, (float(*)[64])smem, (float(*)[64])(smem + 2048));
    __threadfence();
    __syncthreads();
    if (tid == 0) lastFlag = (atomicAdd(&a.cnt[r * 16 + nt], 1) == SPLITS - 1);
    __syncthreads();
    if (lastFlag) {
        __threadfence();
        reduce_tile_store(a.part + (size_t)r * SPLITS * 65536,
                          a.hx + (size_t)r * 65536, nt << 6, tid, true);
    }
}

__global__ __launch_bounds__(NTHR)
void k_gemmC_red(Args a)
{
    __shared__ __align__(16) float smem[4096];
    __shared__ int lastFlag;
    const int wk = blockIdx.x, tid = threadIdx.x;
    const int r = wk >> 8, nt = wk & 15, sp = (wk >> 4) & 15;
    const float* a0 = a.hx + (size_t)r * 65536;
    const float* w  = (r == 0) ? a.Win_as : (r == 1) ? a.Win_so : a.Win_oa;
    gemm_tile<1024, 0>(a0, nullptr, w, a.part + (size_t)r * SPLITS * 65536,
                       nt, sp, tid, (float(*)[64])smem, (float(*)[64])(smem + 2048));
    __threadfence();
    __syncthreads();
    if (tid == 0) lastFlag = (atomicAdd(&a.cnt[48 + r * 16 + nt], 1) == SPLITS - 1);
    __syncthreads();
    if (lastFlag) {
        __threadfence();
        reduce_tile_store(a.part + (size_t)r * SPLITS * 65536,
                          a.tt + (size_t)r * 65536, nt << 6, tid, false);
    }
}

__global__ __launch_bounds__(NTHR)
void k_flash_comb(Args a)
{
    __shared__ __align__(16) float smem[4224];
    __shared__ int lastFlag;
    const int tid = threadIdx.x;
    flash_phase(a, blockIdx.x, tid, smem);
    __threadfence();
    __syncthreads();
    const int b = blockIdx.x >> 3;
    if (tid == 0) lastFlag = (atomicAdd(&a.cnt[96 + b], 1) == 7);
    __syncthreads();
    if (lastFlag) {
        __threadfence();
        #pragma unroll
        for (int r = 0; r < 3; r++) combine8(a, b, r, tid);
    }
}

__global__ __launch_bounds__(NTHR)
void k_gemmG_bcast(Args a)
{
    __shared__ __align__(16) float smem[4096];
    __shared__ int lastFlag;
    const int wk = blockIdx.x, tid = threadIdx.x;
    const int r = wk >> 8, nt = wk & 15, sp = (wk >> 4) & 15;
    const float* a0 = a.wc + (size_t)r * 65536;
    const float* a1 = a.hx + (size_t)r * 65536;
    const float* w  = (r == 0) ? a.Wout_as : (r == 1) ? a.Wout_so : a.Wout_oa;
    gemm_tile<1024, 1024>(a0, a1, w, a.part + (size_t)r * SPLITS * 65536,
                          nt, sp, tid, (float(*)[64])smem, (float(*)[64])(smem + 2048));
    __threadfence();
    __syncthreads();
    if (tid == 0) lastFlag = (atomicAdd(&a.cnt[160 + r * 16 + nt], 1) == SPLITS - 1);
    __syncthreads();
    if (lastFlag) {
        __threadfence();
        reduce_tile_bcast(a, r, nt << 6, tid);
    }
}

// ---------------------------------------------------------------------------
extern "C" void kernel_launch(void* const* d_in, const int* in_sizes, int n_in,
                              void* d_out, int out_size, void* d_ws, size_t ws_size,
                              hipStream_t stream)
{
    (void)in_sizes; (void)n_in; (void)out_size; (void)ws_size;
    float* ws = (float*)d_ws;

    Args a;
    a.hs  = (const float*)d_in[0];
    a.ho  = (const float*)d_in[1];
    a.ha  = (const float*)d_in[2];
    a.enc = (const float*)d_in[3];
    a.Fp  = (const int*)d_in[4];
    a.W_as    = (const float*)d_in[5];
    a.W_so    = (const float*)d_in[6];
    a.W_oa    = (const float*)d_in[7];
    a.Win_as  = (const float*)d_in[8];
    a.Win_so  = (const float*)d_in[9];
    a.Win_oa  = (const float*)d_in[10];
    a.Wout_as = (const float*)d_in[11];
    a.Wout_so = (const float*)d_in[12];
    a.Wout_oa = (const float*)d_in[13];

    a.part = ws;                   // [3][16][64][1024] = 3,145,728 floats
    a.hx   = ws + 3145728;         // [3][64][1024]
    a.tt   = ws + 3342336;         // [3][64][1024]
    a.wc   = ws + 3538944;         // [3][64][1024]
    a.opm  = ws + 3735552;         // [512][3][1024] = 1,572,864 floats
    a.ms   = ws + 5308416;         // [512][3][2] = 3,072 floats
    a.cnt  = (int*)(ws + 5311488); // [256] semaphores
    a.out  = (float*)d_out;

    // Zero semaphores (workspace is poisoned by the harness between runs).
    hipMemsetAsync((void*)a.cnt, 0, 256 * sizeof(int), stream);

    k_gemmA_red <<<NWORK_GEMM, NTHR, 0, stream>>>(a);
    k_gemmC_red <<<NWORK_GEMM, NTHR, 0, stream>>>(a);
    k_flash_comb<<<512,        NTHR, 0, stream>>>(a);
    k_gemmG_bcast<<<NWORK_GEMM, NTHR, 0, stream>>>(a);
}

// Round 8
// 326.096 us; speedup vs baseline: 2.2738x; 2.2738x over previous
//
#include <hip/hip_runtime.h>

// Problem constants (B=64, L=512, H=1024)
constexpr int BB = 64;
constexpr int LL = 512;
constexpr int HH = 1024;
constexpr int SPLITS = 16;            // split-K factor for all GEMMs
constexpr int NTHR  = 256;
constexpr int NWORK_GEMM = 3 * 16 * SPLITS;   // 768 (r, n-tile, split) tiles

typedef float nt_float4 __attribute__((ext_vector_type(4)));

struct Args {
    const float* hs; const float* ho; const float* ha; const float* enc;
    const int* Fp;
    const float* W_as;  const float* W_so;  const float* W_oa;
    const float* Win_as; const float* Win_so; const float* Win_oa;
    const float* Wout_as; const float* Wout_so; const float* Wout_oa;
    float* partA; float* partC; float* partG;
    float* hx; float* wc; float* opm; float* ms;
    float* out;
};

// ---------------------------------------------------------------------------
// One (r, n-tile, split) tile of the skinny GEMM, software-pipelined
// (register prefetch of next K-step). smem: As[32][64]+Ws[32][64] = 16 KB.
// Correctness-proven (rounds 3-6), VGPR ~116, no spills.
// ---------------------------------------------------------------------------
template<int K0, int K1>
__device__ __forceinline__ void gemm_tile(const float* __restrict__ a0,
                                          const float* __restrict__ a1,
                                          const float* __restrict__ w,
                                          float* __restrict__ part_r,
                                          int nt, int sp, int tid,
                                          float (*As)[64], float (*Ws)[64])
{
    constexpr int K = K0 + K1;
    constexpr int KRANGE = K / SPLITS;
    const int n0 = nt << 6;
    const int ks = sp * KRANGE;
    const int tn = tid & 15;           // n quad index
    const int tm = tid >> 4;           // m quad index
    const int m   = tid >> 2;          // A-stage row 0..63
    const int kk0 = (tid & 3) << 3;    // A-stage k offset 0,8,16,24
    const int j4  = (tid & 15) << 2;   // W-stage col offset
    const int kkw = tid >> 4;          // W-stage k row 0..15

    float4 av0, av1, wv0, wv1;
    {
        const int kg = ks + kk0;
        const float* srcA = (K1 == 0 || kg < K0) ? (a0 + (size_t)m * HH + kg)
                                                 : (a1 + (size_t)m * HH + (kg - K0));
        av0 = *(const float4*)srcA;
        av1 = *(const float4*)(srcA + 4);
        wv0 = *(const float4*)(w + (size_t)(ks + kkw) * HH + n0 + j4);
        wv1 = *(const float4*)(w + (size_t)(ks + kkw + 16) * HH + n0 + j4);
    }

    float acc[4][4] = {};

    for (int kt = ks; kt < ks + KRANGE; kt += 32) {
        As[kk0 + 0][m] = av0.x; As[kk0 + 1][m] = av0.y;
        As[kk0 + 2][m] = av0.z; As[kk0 + 3][m] = av0.w;
        As[kk0 + 4][m] = av1.x; As[kk0 + 5][m] = av1.y;
        As[kk0 + 6][m] = av1.z; As[kk0 + 7][m] = av1.w;
        *(float4*)&Ws[kkw][j4]      = wv0;
        *(float4*)&Ws[kkw + 16][j4] = wv1;
        __syncthreads();

        if (kt + 32 < ks + KRANGE) {
            const int kn = kt + 32;
            const int kg = kn + kk0;
            const float* srcA = (K1 == 0 || kg < K0) ? (a0 + (size_t)m * HH + kg)
                                                     : (a1 + (size_t)m * HH + (kg - K0));
            av0 = *(const float4*)srcA;
            av1 = *(const float4*)(srcA + 4);
            wv0 = *(const float4*)(w + (size_t)(kn + kkw) * HH + n0 + j4);
            wv1 = *(const float4*)(w + (size_t)(kn + kkw + 16) * HH + n0 + j4);
        }

        #pragma unroll
        for (int kk = 0; kk < 32; kk++) {
            float4 a4 = *(const float4*)&As[kk][tm << 2];
            float4 b4 = *(const float4*)&Ws[kk][tn << 2];
            float av[4] = {a4.x, a4.y, a4.z, a4.w};
            float bv[4] = {b4.x, b4.y, b4.z, b4.w};
            #pragma unroll
            for (int i = 0; i < 4; i++)
                #pragma unroll
                for (int j = 0; j < 4; j++)
                    acc[i][j] += av[i] * bv[j];
        }
        __syncthreads();
    }

    float* dst = part_r + (size_t)(sp << 6) * HH + n0 + (tn << 2);
    #pragma unroll
    for (int i = 0; i < 4; i++) {
        const int mm = (tm << 2) + i;
        *(float4*)(dst + (size_t)mm * HH) = make_float4(acc[i][0], acc[i][1], acc[i][2], acc[i][3]);
    }
}

// ---------------------------------------------------------------------------
// Stage 1: part = cat(.,.) @ W_x -> partA.  (768 blocks)
// ---------------------------------------------------------------------------
__global__ __launch_bounds__(NTHR)
void k_gemmA(Args a)
{
    __shared__ __align__(16) float smem[4096];
    const int wk = blockIdx.x, tid = threadIdx.x;
    const int r = wk >> 8, nt = wk & 15, sp = (wk >> 4) & 15;
    const float* a0 = (r == 0) ? a.ha : (r == 1) ? a.hs : a.ho;
    const float* a1 = (r == 0) ? a.hs : (r == 1) ? a.ho : a.ha;
    const float* w  = (r == 0) ? a.W_as : (r == 1) ? a.W_so : a.W_oa;
    gemm_tile<1024, 1024>(a0, a1, w, a.partA + (size_t)r * SPLITS * 65536,
                          nt, sp, tid, (float(*)[64])smem, (float(*)[64])(smem + 2048));
}

// ---------------------------------------------------------------------------
// Stage 2 fused: each block reduces+tanh's its own 64x64 A-slice of partA
// (kernel boundary guarantees visibility; no fence needed), then GEMMs with
// Win -> partC. nt==0 blocks also materialize the hx slice for gemmG.
// LDS: As2[64][64] (16 KB, [k][m]) + Ws[32][64] (8 KB).  (768 blocks)
// ---------------------------------------------------------------------------
__global__ __launch_bounds__(NTHR)
void k_gemmC_fused(Args a)
{
    __shared__ __align__(16) float As2[64][64];
    __shared__ __align__(16) float Ws[32][64];
    const int wk = blockIdx.x, tid = threadIdx.x;
    const int r = wk >> 8, nt = wk & 15, sp = (wk >> 4) & 15;
    const int ks = sp << 6;                 // KRANGE = 1024/16 = 64
    const int n0 = nt << 6;
    const float* pA = a.partA + (size_t)r * SPLITS * 65536;
    const float* w  = (r == 0) ? a.Win_as : (r == 1) ? a.Win_so : a.Win_oa;

    // Phase 1: reduce over 16 splits + tanh -> As2[k][m] (and hx if nt==0).
    #pragma unroll
    for (int i = 0; i < 4; i++) {
        const int s  = i * 256 + tid;       // 1024 float4 slots
        const int m  = s >> 4;
        const int k4 = (s & 15) << 2;       // scalar col offset 0..60
        const float* p = pA + (size_t)m * HH + ks + k4;
        float4 v = *(const float4*)p;
        #pragma unroll 4
        for (int y = 1; y < SPLITS; y++) {
            float4 q = *(const float4*)(p + (size_t)y * 65536);
            v.x += q.x; v.y += q.y; v.z += q.z; v.w += q.w;
        }
        v.x = tanhf(v.x); v.y = tanhf(v.y); v.z = tanhf(v.z); v.w = tanhf(v.w);
        As2[k4 + 0][m] = v.x; As2[k4 + 1][m] = v.y;
        As2[k4 + 2][m] = v.z; As2[k4 + 3][m] = v.w;
        if (nt == 0)
            *(float4*)(a.hx + (size_t)r * 65536 + (size_t)m * HH + ks + k4) = v;
    }
    __syncthreads();

    // Phase 2: GEMM over the 64-wide k-window; W staged 32 rows at a time.
    const int tn = tid & 15, tm = tid >> 4;
    const int j4 = (tid & 15) << 2;
    const int kkw = tid >> 4;
    float acc[4][4] = {};
    float4 wv0 = *(const float4*)(w + (size_t)(ks + kkw) * HH + n0 + j4);
    float4 wv1 = *(const float4*)(w + (size_t)(ks + kkw + 16) * HH + n0 + j4);
    #pragma unroll
    for (int kt = 0; kt < 64; kt += 32) {
        *(float4*)&Ws[kkw][j4]      = wv0;
        *(float4*)&Ws[kkw + 16][j4] = wv1;
        __syncthreads();
        if (kt + 32 < 64) {
            wv0 = *(const float4*)(w + (size_t)(ks + kt + 32 + kkw) * HH + n0 + j4);
            wv1 = *(const float4*)(w + (size_t)(ks + kt + 32 + kkw + 16) * HH + n0 + j4);
        }
        #pragma unroll
        for (int kk = 0; kk < 32; kk++) {
            float4 a4 = *(const float4*)&As2[kt + kk][tm << 2];
            float4 b4 = *(const float4*)&Ws[kk][tn << 2];
            float av[4] = {a4.x, a4.y, a4.z, a4.w};
            float bv[4] = {b4.x, b4.y, b4.z, b4.w};
            #pragma unroll
            for (int i = 0; i < 4; i++)
                #pragma unroll
                for (int j = 0; j < 4; j++)
                    acc[i][j] += av[i] * bv[j];
        }
        __syncthreads();
    }

    float* dst = a.partC + (size_t)r * SPLITS * 65536
               + (size_t)(sp << 6) * HH + n0 + (tn << 2);
    #pragma unroll
    for (int i = 0; i < 4; i++) {
        const int mm = (tm << 2) + i;
        *(float4*)(dst + (size_t)mm * HH) = make_float4(acc[i][0], acc[i][1], acc[i][2], acc[i][3]);
    }
}

// ---------------------------------------------------------------------------
// Stage 3 fused: reduce the 3x1024 tt rows for this batch from partC into LDS
// (replaces the reduceD kernel AND de-duplicates per-wave tr loads), then
// flash attention over 64 l-rows. LDS: tr_l[3][1024] + o_l[4][1024] + ms_sh.
// (512 blocks: chunk = b*8 + lc)
// ---------------------------------------------------------------------------
__global__ __launch_bounds__(NTHR)
void k_flash_fused(Args a)
{
    __shared__ __align__(16) float smem[3072 + 4096 + 32];
    float* tr_l = smem;                              // [3][1024]
    float (*o_l)[HH]     = (float(*)[HH])(smem + 3072);       // [4][1024]
    float (*ms_sh)[3][2] = (float(*)[3][2])(smem + 3072 + 4096);
    const int chunk = blockIdx.x, tid = threadIdx.x;
    const int b    = chunk >> 3;
    const int lc   = chunk & 7;
    const int lane = tid & 63;
    const int wv   = tid >> 6;

    // Phase 0: tt[r][b][:] = sum over 16 splits of partC.
    #pragma unroll
    for (int i = 0; i < 3; i++) {
        const int s  = i * 256 + tid;        // 768 float4 slots
        const int rr = s >> 8;
        const int h4 = (s & 255) << 2;
        const float* p = a.partC + (size_t)rr * SPLITS * 65536 + (size_t)b * HH + h4;
        float4 v = *(const float4*)p;
        #pragma unroll 4
        for (int y = 1; y < SPLITS; y++) {
            float4 q = *(const float4*)(p + (size_t)y * 65536);
            v.x += q.x; v.y += q.y; v.z += q.z; v.w += q.w;
        }
        *(float4*)&tr_l[rr * 1024 + h4] = v;
    }
    __syncthreads();

    // Target vectors into registers: tr[r][v] covers h = lane*4 + v*256.
    float4 tr[3][4];
    #pragma unroll
    for (int r = 0; r < 3; r++)
        #pragma unroll
        for (int v = 0; v < 4; v++)
            tr[r][v] = *(const float4*)&tr_l[r * 1024 + (lane << 2) + (v << 8)];

    float  m_run[3] = {-3.0e38f, -3.0e38f, -3.0e38f};
    float  S_run[3] = {0.f, 0.f, 0.f};
    float4 o_run[3][4];
    #pragma unroll
    for (int r = 0; r < 3; r++)
        #pragma unroll
        for (int v = 0; v < 4; v++)
            o_run[r][v] = make_float4(0.f, 0.f, 0.f, 0.f);

    const float* ebase = a.enc + ((size_t)b * LL + (lc << 6) + (wv << 2)) * HH + (lane << 2);

    for (int it = 0; it < 4; it++) {
        const float* e = ebase + (size_t)(it << 4) * HH;
        float4 ev[4][4];
        #pragma unroll
        for (int j = 0; j < 4; j++)
            #pragma unroll
            for (int v = 0; v < 4; v++)
                ev[j][v] = *(const float4*)(e + (size_t)j * HH + (v << 8));

        float s[3][4];
        #pragma unroll
        for (int j = 0; j < 4; j++) {
            float d0 = 0.f, d1 = 0.f, d2 = 0.f;
            #pragma unroll
            for (int v = 0; v < 4; v++) {
                const float4 x = ev[j][v];
                d0 += x.x * tr[0][v].x + x.y * tr[0][v].y + x.z * tr[0][v].z + x.w * tr[0][v].w;
                d1 += x.x * tr[1][v].x + x.y * tr[1][v].y + x.z * tr[1][v].z + x.w * tr[1][v].w;
                d2 += x.x * tr[2][v].x + x.y * tr[2][v].y + x.z * tr[2][v].z + x.w * tr[2][v].w;
            }
            #pragma unroll
            for (int off = 32; off > 0; off >>= 1) {
                d0 += __shfl_xor(d0, off);
                d1 += __shfl_xor(d1, off);
                d2 += __shfl_xor(d2, off);
            }
            s[0][j] = d0; s[1][j] = d1; s[2][j] = d2;
        }

        #pragma unroll
        for (int r = 0; r < 3; r++) {
            const float mb = fmaxf(fmaxf(s[r][0], s[r][1]), fmaxf(s[r][2], s[r][3]));
            const float mn_ = fmaxf(m_run[r], mb);
            const float alpha = __expf(m_run[r] - mn_);
            m_run[r] = mn_;
            float p[4];
            float psum = 0.f;
            #pragma unroll
            for (int j = 0; j < 4; j++) { p[j] = __expf(s[r][j] - mn_); psum += p[j]; }
            S_run[r] = S_run[r] * alpha + psum;
            #pragma unroll
            for (int v = 0; v < 4; v++) {
                float4 o = o_run[r][v];
                o.x *= alpha; o.y *= alpha; o.z *= alpha; o.w *= alpha;
                #pragma unroll
                for (int j = 0; j < 4; j++) {
                    const float4 x = ev[j][v];
                    o.x += p[j] * x.x; o.y += p[j] * x.y;
                    o.z += p[j] * x.z; o.w += p[j] * x.w;
                }
                o_run[r][v] = o;
            }
        }
    }

    __syncthreads();
    if (lane == 0) {
        #pragma unroll
        for (int r = 0; r < 3; r++) { ms_sh[wv][r][0] = m_run[r]; ms_sh[wv][r][1] = S_run[r]; }
    }

    #pragma unroll
    for (int r = 0; r < 3; r++) {
        __syncthreads();
        #pragma unroll
        for (int v = 0; v < 4; v++)
            *(float4*)&o_l[wv][(lane << 2) + (v << 8)] = o_run[r][v];
        __syncthreads();

        const float m0 = ms_sh[0][r][0], m1 = ms_sh[1][r][0];
        const float m2 = ms_sh[2][r][0], m3 = ms_sh[3][r][0];
        const float M = fmaxf(fmaxf(m0, m1), fmaxf(m2, m3));
        const float w0 = __expf(m0 - M), w1 = __expf(m1 - M);
        const float w2 = __expf(m2 - M), w3 = __expf(m3 - M);
        float4 q0 = *(const float4*)&o_l[0][tid << 2];
        float4 q1 = *(const float4*)&o_l[1][tid << 2];
        float4 q2 = *(const float4*)&o_l[2][tid << 2];
        float4 q3 = *(const float4*)&o_l[3][tid << 2];
        float4 acc;
        acc.x = w0 * q0.x + w1 * q1.x + w2 * q2.x + w3 * q3.x;
        acc.y = w0 * q0.y + w1 * q1.y + w2 * q2.y + w3 * q3.y;
        acc.z = w0 * q0.z + w1 * q1.z + w2 * q2.z + w3 * q3.z;
        acc.w = w0 * q0.w + w1 * q1.w + w2 * q2.w + w3 * q3.w;
        *(float4*)&a.opm[((size_t)chunk * 3 + r) * HH + (tid << 2)] = acc;
        if (tid == 0) {
            const float S = w0 * ms_sh[0][r][1] + w1 * ms_sh[1][r][1]
                          + w2 * ms_sh[2][r][1] + w3 * ms_sh[3][r][1];
            a.ms[((size_t)chunk * 3 + r) * 2 + 0] = M;
            a.ms[((size_t)chunk * 3 + r) * 2 + 1] = S;
        }
    }
}

// ---------------------------------------------------------------------------
// Stage 4: LSE-combine 8 chunks per (b, r) -> wc.  (dim3(64,3) blocks)
// ---------------------------------------------------------------------------
__global__ __launch_bounds__(NTHR)
void k_combine(Args a)
{
    const int b = blockIdx.x, r = blockIdx.y, tid = threadIdx.x;
    float mv[8], sv[8];
    float M = -3.0e38f;
    #pragma unroll
    for (int c = 0; c < 8; c++) {
        const int chunk = (b << 3) + c;
        mv[c] = a.ms[((size_t)chunk * 3 + r) * 2 + 0];
        sv[c] = a.ms[((size_t)chunk * 3 + r) * 2 + 1];
        M = fmaxf(M, mv[c]);
    }
    float S = 0.f;
    float4 acc = make_float4(0.f, 0.f, 0.f, 0.f);
    #pragma unroll
    for (int c = 0; c < 8; c++) {
        const float wgt = __expf(mv[c] - M);
        S += wgt * sv[c];
        const int chunk = (b << 3) + c;
        float4 q = *(const float4*)&a.opm[((size_t)chunk * 3 + r) * HH + (tid << 2)];
        acc.x += wgt * q.x; acc.y += wgt * q.y;
        acc.z += wgt * q.z; acc.w += wgt * q.w;
    }
    const float inv = 1.0f / S;
    acc.x *= inv; acc.y *= inv; acc.z *= inv; acc.w *= inv;
    *(float4*)&a.wc[(size_t)(r * BB + b) * HH + (tid << 2)] = acc;
}

// ---------------------------------------------------------------------------
// Stage 5: part = cat(wc, hx) @ Wout_x -> partG.  (768 blocks)
// ---------------------------------------------------------------------------
__global__ __launch_bounds__(NTHR)
void k_gemmG(Args a)
{
    __shared__ __align__(16) float smem[4096];
    const int wk = blockIdx.x, tid = threadIdx.x;
    const int r = wk >> 8, nt = wk & 15, sp = (wk >> 4) & 15;
    const float* a0 = a.wc + (size_t)r * 65536;
    const float* a1 = a.hx + (size_t)r * 65536;
    const float* w  = (r == 0) ? a.Wout_as : (r == 1) ? a.Wout_so : a.Wout_oa;
    gemm_tile<1024, 1024>(a0, a1, w, a.partG + (size_t)r * SPLITS * 65536,
                          nt, sp, tid, (float(*)[64])smem, (float(*)[64])(smem + 2048));
}

// ---------------------------------------------------------------------------
// Stage 6: reduce partG + tanh + broadcast F copies -> out[r][b][f][h].
// (192 blocks x 256; thread owns one float4 slot)
// ---------------------------------------------------------------------------
__global__ __launch_bounds__(NTHR)
void k_bcast(Args a)
{
    const int i4   = blockIdx.x * NTHR + threadIdx.x;
    const int flat = i4 << 2;
    const int r    = flat >> 16;
    const int mn   = flat & 65535;
    const float* p = a.partG + (size_t)r * SPLITS * 65536 + mn;
    float4 s = *(const float4*)p;
    #pragma unroll
    for (int y = 1; y < SPLITS; y++) {
        float4 q = *(const float4*)(p + (size_t)y * 65536);
        s.x += q.x; s.y += q.y; s.z += q.z; s.w += q.w;
    }
    s.x = tanhf(s.x); s.y = tanhf(s.y); s.z = tanhf(s.z); s.w = tanhf(s.w);

    nt_float4 sv;
    sv.x = s.x; sv.y = s.y; sv.z = s.z; sv.w = s.w;

    const int F  = *a.Fp;
    const int bb = mn >> 10;
    const int hh = mn & 1023;
    float* o = a.out + ((size_t)(r * BB + bb) * F) * HH + hh;
    for (int f = 0; f < F; f++)
        __builtin_nontemporal_store(sv, (nt_float4*)(o + (size_t)f * HH));
}

// ---------------------------------------------------------------------------
extern "C" void kernel_launch(void* const* d_in, const int* in_sizes, int n_in,
                              void* d_out, int out_size, void* d_ws, size_t ws_size,
                              hipStream_t stream)
{
    (void)in_sizes; (void)n_in; (void)out_size; (void)ws_size;
    float* ws = (float*)d_ws;

    Args a;
    a.hs  = (const float*)d_in[0];
    a.ho  = (const float*)d_in[1];
    a.ha  = (const float*)d_in[2];
    a.enc = (const float*)d_in[3];
    a.Fp  = (const int*)d_in[4];
    a.W_as    = (const float*)d_in[5];
    a.W_so    = (const float*)d_in[6];
    a.W_oa    = (const float*)d_in[7];
    a.Win_as  = (const float*)d_in[8];
    a.Win_so  = (const float*)d_in[9];
    a.Win_oa  = (const float*)d_in[10];
    a.Wout_as = (const float*)d_in[11];
    a.Wout_so = (const float*)d_in[12];
    a.Wout_oa = (const float*)d_in[13];

    a.partA = ws;                    // [3][16][64][1024] = 3,145,728 floats
    a.partC = ws + 3145728;          // [3][16][64][1024]
    a.partG = ws + 6291456;          // [3][16][64][1024]
    a.hx    = ws + 9437184;          // [3][64][1024]
    a.wc    = ws + 9633792;          // [3][64][1024]
    a.opm   = ws + 9830400;          // [512][3][1024] = 1,572,864 floats
    a.ms    = ws + 11403264;         // [512][3][2]
    a.out   = (float*)d_out;

    k_gemmA      <<<NWORK_GEMM, NTHR, 0, stream>>>(a);
    k_gemmC_fused<<<NWORK_GEMM, NTHR, 0, stream>>>(a);
    k_flash_fused<<<512,        NTHR, 0, stream>>>(a);
    k_combine    <<<dim3(64, 3), NTHR, 0, stream>>>(a);
    k_gemmG      <<<NWORK_GEMM, NTHR, 0, stream>>>(a);
    k_bcast      <<<192,        NTHR, 0, stream>>>(a);
}